// Round 2
// baseline (3657.562 us; speedup 1.0000x reference)
//
#include <hip/hip_runtime.h>
#include <math.h>

typedef unsigned int u32;
typedef unsigned long long u64;

#define BATCH 64
#define A_TOT 8649
#define TOPN  6000
#define POST  1500
#define NB    4096
#define NT    512
#define NWAVE 8
#define NSLOT 12
#define KEY_STRIDE 8704
#define QTOT  6144          // NWAVE * 768 storage slots (>= TOPN)
#define CACHE_N 2048        // ranks cached in LDS (reuses sort buckets, 32 KB)
#define SENT_T 0x3FFFFFFF

// ---- DPP full-wave reductions: result valid in lane 63 ----
__device__ __forceinline__ int wave_min_dpp(int v) {
    int t;
    t = __builtin_amdgcn_update_dpp(v, v, 0x111, 0xf, 0xf, false); v = min(v, t); // row_shr:1
    t = __builtin_amdgcn_update_dpp(v, v, 0x112, 0xf, 0xf, false); v = min(v, t); // row_shr:2
    t = __builtin_amdgcn_update_dpp(v, v, 0x114, 0xf, 0xe, false); v = min(v, t); // row_shr:4
    t = __builtin_amdgcn_update_dpp(v, v, 0x118, 0xf, 0xc, false); v = min(v, t); // row_shr:8
    t = __builtin_amdgcn_update_dpp(v, v, 0x142, 0xa, 0xf, false); v = min(v, t); // row_bcast:15
    t = __builtin_amdgcn_update_dpp(v, v, 0x143, 0xc, 0xf, false); v = min(v, t); // row_bcast:31
    return v;
}
__device__ __forceinline__ int wave_max_dpp(int v) {
    int t;
    t = __builtin_amdgcn_update_dpp(v, v, 0x111, 0xf, 0xf, false); v = max(v, t);
    t = __builtin_amdgcn_update_dpp(v, v, 0x112, 0xf, 0xf, false); v = max(v, t);
    t = __builtin_amdgcn_update_dpp(v, v, 0x114, 0xf, 0xe, false); v = max(v, t);
    t = __builtin_amdgcn_update_dpp(v, v, 0x118, 0xf, 0xc, false); v = max(v, t);
    t = __builtin_amdgcn_update_dpp(v, v, 0x142, 0xa, 0xf, false); v = max(v, t);
    t = __builtin_amdgcn_update_dpp(v, v, 0x143, 0xc, 0xf, false); v = max(v, t);
    return v;
}

// One block per batch image, 512 threads (8 waves), 12 candidate slots/thread.
// launch_bounds(512,1): avoid the (1024,4) min-blocks trap that capped R1 at
// 32 VGPRs and spilled all candidate state to scratch.
__global__ __launch_bounds__(NT, 1) void roibbox_kernel(
    const float* __restrict__ deltas,    // [B, A, 4]
    const float* __restrict__ probs,     // [B, A]
    const float* __restrict__ anchors,   // [A, 4]
    float* __restrict__ out,             // [B*POST*4] boxes then [B*POST] scores
    u64*   __restrict__ wskeys,          // [B, KEY_STRIDE]
    float4* __restrict__ wsboxes,        // [B, QTOT] rank-indexed decoded boxes
    u32*   __restrict__ wsaorder)        // [B, QTOT] area-order -> rank
{
    #pragma clang fp contract(off)
    __shared__ __align__(16) u32 lds_pool[2*NB];  // bucketA|bucketB; later float4 cache
    __shared__ u32 stemp[2*NT];
    __shared__ u32 pickrank[POST];
    __shared__ __align__(16) u32 wslot[2][NWAVE];

    u32* bucketA = lds_pool;
    u32* bucketB = lds_pool + NB;

    const int tid = threadIdx.x;
    const int b   = blockIdx.x;
    const int wv  = tid >> 6;
    const int ln  = tid & 63;
    const float* pb = probs + (size_t)b * A_TOT;
    u64*    keys    = wskeys   + (size_t)b * KEY_STRIDE;
    float4* boxws_b = wsboxes  + (size_t)b * QTOT;
    u32*    aorder  = wsaorder + (size_t)b * QTOT;

    // ================= Phase A: stable descending score sort =================
    for (int i = tid; i < NB; i += NT) bucketA[i] = 0u;
    __syncthreads();
    for (int j = tid; j < A_TOT; j += NT) {
        float s = pb[j];
        int bkt = (int)(s * (float)NB);
        bkt = (NB-1) - min(max(bkt, 0), NB-1);
        atomicAdd(&bucketA[bkt], 1u);
    }
    __syncthreads();
    {   // exclusive scan, 8 counts/thread + Hillis-Steele over 512
        int base = tid << 3;
        u32 c[8]; u32 mysum = 0;
        #pragma unroll
        for (int i = 0; i < 8; ++i) { c[i] = bucketA[base+i]; mysum += c[i]; }
        stemp[tid] = mysum;
        __syncthreads();
        int src = 0;
        for (int off = 1; off < NT; off <<= 1) {
            u32 v = stemp[src*NT + tid];
            if (tid >= off) v += stemp[src*NT + tid - off];
            stemp[(src^1)*NT + tid] = v;
            __syncthreads();
            src ^= 1;
        }
        u32 run = stemp[src*NT + tid] - mysum;
        #pragma unroll
        for (int i = 0; i < 8; ++i) { bucketA[base+i] = run; bucketB[base+i] = run; run += c[i]; }
    }
    __syncthreads();
    for (int j = tid; j < A_TOT; j += NT) {
        float s = pb[j];
        int bkt = (int)(s * (float)NB);
        bkt = (NB-1) - min(max(bkt, 0), NB-1);
        u32 pos = atomicAdd(&bucketB[bkt], 1u);
        keys[pos] = ((u64)__float_as_uint(s) << 32) | (u64)(~(u32)j);
    }
    __syncthreads();
    for (int bkt = tid; bkt < NB; bkt += NT) {   // per-bucket insertion sort
        int begin = (int)bucketA[bkt], end = (int)bucketB[bkt];
        for (int k = begin + 1; k < end; ++k) {
            u64 key = keys[k];
            int m = k - 1;
            while (m >= begin && keys[m] < key) { keys[m+1] = keys[m]; --m; }
            keys[m+1] = key;
        }
    }
    __syncthreads();

    // ====== Phase B: decode rank-order boxes + area histogram ======
    for (int i = tid; i < NB; i += NT) bucketA[i] = 0u;
    __syncthreads();
    for (int k = 0; k < QTOT/NT; ++k) {
        int r = tid + k*NT;
        if (r < TOPN) {
            u64 kk = keys[r];
            u32 aidx = ~((u32)kk);
            float4 av = *(const float4*)(anchors + (size_t)aidx*4);
            float4 dv = *(const float4*)(deltas + ((size_t)b*A_TOT + aidx)*4);
            float d0 = dv.x*0.1f, d1 = dv.y*0.1f, d2 = dv.z*0.2f, d3 = dv.w*0.2f;
            float ah = av.z - av.x, aw = av.w - av.y;
            float acy = av.x + 0.5f*ah, acx = av.y + 0.5f*aw;
            float h  = (float)exp((double)d2) * ah;   // correctly-rounded fp32 exp
            float w_ = (float)exp((double)d3) * aw;
            float cy = d0*ah + acy;
            float cx = d1*aw + acx;
            float y1 = cy - 0.5f*h, x1 = cx - 0.5f*w_;
            float y2 = cy + 0.5f*h, x2 = cx + 0.5f*w_;
            boxws_b[r] = make_float4(y1, x1, y2, x2);
            float area = (y2 - y1) * (x2 - x1);
            int ab = (int)(area * 1024.0f);
            ab = min(max(ab, 0), NB-1);
            atomicAdd(&bucketA[ab], 1u);
            keys[r] = (kk & 0xFFFFFFFF00000000ull) | (u64)(u32)ab;  // stash bucket
        }
    }
    __syncthreads();
    {   // scan area counts -> cursors in bucketB
        int base = tid << 3;
        u32 c[8]; u32 mysum = 0;
        #pragma unroll
        for (int i = 0; i < 8; ++i) { c[i] = bucketA[base+i]; mysum += c[i]; }
        stemp[tid] = mysum;
        __syncthreads();
        int src = 0;
        for (int off = 1; off < NT; off <<= 1) {
            u32 v = stemp[src*NT + tid];
            if (tid >= off) v += stemp[src*NT + tid - off];
            stemp[(src^1)*NT + tid] = v;
            __syncthreads();
            src ^= 1;
        }
        u32 run = stemp[src*NT + tid] - mysum;
        #pragma unroll
        for (int i = 0; i < 8; ++i) { bucketB[base+i] = run; run += c[i]; }
    }
    __syncthreads();
    // ====== Phase C: area-order scatter ======
    for (int q = TOPN + tid; q < QTOT; q += NT) aorder[q] = 0xFFFFFFFFu;
    for (int k = 0; k < QTOT/NT; ++k) {
        int r = tid + k*NT;
        if (r < TOPN) {
            int ab = (int)(keys[r] & (u64)(NB-1));
            u32 pos = atomicAdd(&bucketB[ab], 1u);
            aorder[pos] = (u32)r;
        }
    }
    __syncthreads();
    // lds_pool dead -> LDS box cache for low ranks (most picks)
    float4* cache = (float4*)lds_pool;
    for (int idx = tid; idx < CACHE_N; idx += NT) cache[idx] = boxws_b[idx];

    // ====== Phase D: load my 12 candidates into registers ======
    float rY1[NSLOT], rX1[NSLOT], rY2[NSLOT], rX2[NSLOT], rA[NSLOT];
    u32 rR[NSLOT];
    u32 mask = 0;
    u32 aminb = 0x7F800000u, amaxb = 0u;
    #pragma unroll
    for (int i = 0; i < NSLOT; ++i) {
        int q = wv*768 + i*64 + ln;
        u32 r = aorder[q];
        if (r != 0xFFFFFFFFu) {
            float4 bx = boxws_b[r];
            rY1[i] = bx.x; rX1[i] = bx.y; rY2[i] = bx.z; rX2[i] = bx.w;
            float a = (bx.z - bx.x) * (bx.w - bx.y);
            rA[i] = a;
            rR[i] = (r << 4) | (u32)i;
            mask |= 1u << i;
            aminb = min(aminb, __float_as_uint(a));
            amaxb = max(amaxb, __float_as_uint(a));
        } else {
            rY1[i]=rX1[i]=rY2[i]=rX2[i]=rA[i]=0.f; rR[i] = SENT_T;
        }
    }
    u32 tmin = SENT_T;
    #pragma unroll
    for (int i = 0; i < NSLOT; ++i) if (mask & (1u<<i)) tmin = min(tmin, rR[i]);
    float wMinA = __uint_as_float((u32)__builtin_amdgcn_readlane(wave_min_dpp((int)aminb), 63));
    float wMaxA = __uint_as_float((u32)__builtin_amdgcn_readlane(wave_max_dpp((int)amaxb), 63));
    int wtcache = wave_min_dpp((int)tmin);     // lane 63 holds wave min
    if (ln == 63) wslot[0][wv] = (u32)wtcache;
    __syncthreads();

    // ====== greedy NMS: 1 barrier / pick, double-buffered per-wave argmin ======
    int par = 0;
    int pend = POST;
    for (int p = 0; p < POST; ++p) {
        uint4 s0 = *((const uint4*)&wslot[par][0]);
        uint4 s1 = *((const uint4*)&wslot[par][4]);
        u32 v = min(min(min(s0.x,s0.y), min(s0.z,s0.w)),
                    min(min(s1.x,s1.y), min(s1.z,s1.w)));
        u32 vu = (u32)__builtin_amdgcn_readfirstlane((int)v);   // block-uniform
        if (vu == (u32)SENT_T) { pend = p; break; }
        u32 r = vu >> 4;
        if (tid == 0) pickrank[p] = r;
        float4 sb;
        if (r < CACHE_N) sb = ((const float4*)lds_pool)[r];
        else             sb = boxws_b[r];
        float sy1 = sb.x, sx1 = sb.y, sy2 = sb.z, sx2 = sb.w;
        float sA  = (sy2 - sy1) * (sx2 - sx1);
        float loA = 0.699f  * sA;
        float hiA = 1.4307f * sA;
        bool changed = false;
        if (tmin == vu) {                       // I owned the pick: retire it
            mask &= ~(1u << (vu & 15u));
            changed = true;
        }
        if (!(wMaxA < loA || wMinA > hiA)) {    // wave-level area quick-reject
            #pragma unroll
            for (int i = 0; i < NSLOT; ++i) {
                if (mask & (1u << i)) {
                    float bA = rA[i];
                    if (bA >= loA && bA <= hiA) {
                        float yy1 = fmaxf(sy1, rY1[i]);
                        float xx1 = fmaxf(sx1, rX1[i]);
                        float yy2 = fminf(sy2, rY2[i]);
                        float xx2 = fminf(sx2, rX2[i]);
                        float iy = fmaxf(yy2 - yy1, 0.0f);
                        float ix = fmaxf(xx2 - xx1, 0.0f);
                        float inter = iy * ix;
                        float den = ((sA + bA) - inter) + 1e-9f;  // exact ref order
                        bool sup;
                        if      (inter > 0.7002f * den) sup = true;   // ratio > 0.7 guaranteed
                        else if (inter < 0.6998f * den) sup = false;  // ratio < 0.7 guaranteed
                        else sup = (inter / den > 0.7f);              // exact, rare
                        if (sup) { mask &= ~(1u << i); changed = true; }
                    }
                }
            }
        }
        if (__ballot(changed)) {                // wave-uniform: re-reduce lazily
            if (changed) {
                u32 t = SENT_T;
                #pragma unroll
                for (int i = 0; i < NSLOT; ++i) if (mask & (1u<<i)) t = min(t, rR[i]);
                tmin = t;
            }
            wtcache = wave_min_dpp((int)tmin);
        }
        if (ln == 63) wslot[par ^ 1][wv] = (u32)wtcache;   // always refresh
        __syncthreads();
        par ^= 1;
    }
    __syncthreads();

    // ====== epilogue: parallel coalesced output ======
    const size_t sbase = (size_t)BATCH * POST * 4;
    float4* out4 = (float4*)out;
    for (int p = tid; p < POST; p += NT) {
        size_t row = (size_t)b * POST + p;
        if (p < pend) {
            u32 r = pickrank[p];
            float4 bx = boxws_b[r];
            float4 ob;
            ob.x = fminf(fmaxf(bx.x, 0.f), 1.f);
            ob.y = fminf(fmaxf(bx.y, 0.f), 1.f);
            ob.z = fminf(fmaxf(bx.z, 0.f), 1.f);
            ob.w = fminf(fmaxf(bx.w, 0.f), 1.f);
            out4[row] = ob;
            out[sbase + row] = __uint_as_float((u32)(keys[r] >> 32));
        } else {
            out4[row] = make_float4(0.f, 0.f, 0.f, 0.f);
            out[sbase + row] = 0.f;
        }
    }
}

extern "C" void kernel_launch(void* const* d_in, const int* in_sizes, int n_in,
                              void* d_out, int out_size, void* d_ws, size_t ws_size,
                              hipStream_t stream) {
    const float* deltas  = (const float*)d_in[0];  // [64,31,31,36] f32
    const float* probs   = (const float*)d_in[1];  // [64,31,31,9]  f32
    // d_in[2] = gt_labels (unused)
    const float* anchors = (const float*)d_in[3];  // [8649,4] f32
    float* out = (float*)d_out;                    // 480000 f32

    char* ws = (char*)d_ws;
    u64*    wskeys   = (u64*)ws;                                    // 4,456,448 B
    float4* wsboxes  = (float4*)(ws + (size_t)BATCH*KEY_STRIDE*8);  // 6,291,456 B
    u32*    wsaorder = (u32*)(ws + (size_t)BATCH*KEY_STRIDE*8
                                 + (size_t)BATCH*QTOT*16);          // 1,572,864 B

    roibbox_kernel<<<dim3(BATCH), dim3(NT), 0, stream>>>(
        deltas, probs, anchors, out, wskeys, wsboxes, wsaorder);
}

// Round 3
// 3555.676 us; speedup vs baseline: 1.0287x; 1.0287x over previous
//
#include <hip/hip_runtime.h>
#include <math.h>

typedef unsigned int u32;
typedef unsigned long long u64;

#define BATCH 64
#define A_TOT 8649
#define TOPN  6000
#define POST  1500
#define NB    4096
#define NT    512
#define NWAVE 8
#define NSLOT 12
#define KEY_STRIDE 8704
#define QTOT  6144          // NWAVE * NSLOT * 64 storage slots (>= TOPN)
#define SENT_T 0x3FFFFFFF

// ---- DPP full-wave reductions: result valid in lane 63 ----
__device__ __forceinline__ int wave_min_dpp(int v) {
    int t;
    t = __builtin_amdgcn_update_dpp(v, v, 0x111, 0xf, 0xf, false); v = min(v, t); // row_shr:1
    t = __builtin_amdgcn_update_dpp(v, v, 0x112, 0xf, 0xf, false); v = min(v, t); // row_shr:2
    t = __builtin_amdgcn_update_dpp(v, v, 0x114, 0xf, 0xe, false); v = min(v, t); // row_shr:4
    t = __builtin_amdgcn_update_dpp(v, v, 0x118, 0xf, 0xc, false); v = min(v, t); // row_shr:8
    t = __builtin_amdgcn_update_dpp(v, v, 0x142, 0xa, 0xf, false); v = min(v, t); // row_bcast:15
    t = __builtin_amdgcn_update_dpp(v, v, 0x143, 0xc, 0xf, false); v = min(v, t); // row_bcast:31
    return v;
}
__device__ __forceinline__ int wave_max_dpp(int v) {
    int t;
    t = __builtin_amdgcn_update_dpp(v, v, 0x111, 0xf, 0xf, false); v = max(v, t);
    t = __builtin_amdgcn_update_dpp(v, v, 0x112, 0xf, 0xf, false); v = max(v, t);
    t = __builtin_amdgcn_update_dpp(v, v, 0x114, 0xf, 0xe, false); v = max(v, t);
    t = __builtin_amdgcn_update_dpp(v, v, 0x118, 0xf, 0xc, false); v = max(v, t);
    t = __builtin_amdgcn_update_dpp(v, v, 0x142, 0xa, 0xf, false); v = max(v, t);
    t = __builtin_amdgcn_update_dpp(v, v, 0x143, 0xc, 0xf, false); v = max(v, t);
    return v;
}

// Candidate state as EXPLICIT SCALARS (macro-expanded): R1/R2's local arrays
// were never SROA'd (VGPR_Count 32/48 << 72 live values) -> all pick-loop
// state lived in scratch. Scalars force register residency.
#define DECL_SLOT(i) float y1_##i, x1_##i, y2_##i, x2_##i, ar_##i; u32 rr_##i;

#define LOAD_SLOT(i) { \
    int q = wv*(NSLOT*64) + (i)*64 + ln; \
    u32 r = aorder[q]; \
    if (r != 0xFFFFFFFFu) { \
        float4 bx = boxws_b[r]; \
        y1_##i = bx.x; x1_##i = bx.y; y2_##i = bx.z; x2_##i = bx.w; \
        float a_ = (bx.z - bx.x) * (bx.w - bx.y); \
        ar_##i = a_; \
        rr_##i = (r << 7) | ((u32)(i) << 3) | (u32)wv; \
        mask |= 1u << (i); \
        aminb = min(aminb, __float_as_uint(a_)); \
        amaxb = max(amaxb, __float_as_uint(a_)); \
    } else { \
        y1_##i=x1_##i=y2_##i=x2_##i=ar_##i=0.f; rr_##i = (u32)SENT_T; \
    } }

#define TEST_SLOT(i) if (mask & (1u << (i))) { \
    float bA = ar_##i; \
    if (bA >= loA && bA <= hiA) { \
        float yy1 = fmaxf(sy1, y1_##i); \
        float xx1 = fmaxf(sx1, x1_##i); \
        float yy2 = fminf(sy2, y2_##i); \
        float xx2 = fminf(sx2, x2_##i); \
        float iy = fmaxf(yy2 - yy1, 0.0f); \
        float ix = fmaxf(xx2 - xx1, 0.0f); \
        float inter = iy * ix; \
        float den = ((sA + bA) - inter) + 1e-9f; \
        bool sup; \
        if      (inter > 0.7002f * den) sup = true; \
        else if (inter < 0.6998f * den) sup = false; \
        else sup = (inter / den > 0.7f); \
        if (sup) { mask &= ~(1u << (i)); changed = true; } \
    } }

#define MIN_SLOT(i) if ((mask & (1u << (i))) && rr_##i < t_) { \
    t_ = rr_##i; cby1 = y1_##i; cbx1 = x1_##i; cby2 = y2_##i; cbx2 = x2_##i; }

#define FORALL(M) M(0) M(1) M(2) M(3) M(4) M(5) M(6) M(7) M(8) M(9) M(10) M(11)

__global__ __launch_bounds__(NT, 1) void roibbox_kernel(
    const float* __restrict__ deltas,    // [B, A, 4]
    const float* __restrict__ probs,     // [B, A]
    const float* __restrict__ anchors,   // [A, 4]
    float* __restrict__ out,             // [B*POST*4] boxes then [B*POST] scores
    u64*   __restrict__ wskeys,          // [B, KEY_STRIDE]
    float4* __restrict__ wsboxes,        // [B, QTOT] rank-indexed decoded boxes
    u32*   __restrict__ wsaorder)        // [B, QTOT] area-order -> rank
{
    #pragma clang fp contract(off)
    __shared__ __align__(16) u32 lds_pool[2*NB];  // bucketA | bucketB
    __shared__ u32 stemp[2*NT];
    __shared__ u32 pickrank[POST];
    __shared__ __align__(16) u32 wkey[2][NWAVE];
    __shared__ __align__(16) float4 wbox[2][NWAVE];

    u32* bucketA = lds_pool;
    u32* bucketB = lds_pool + NB;

    const int tid = threadIdx.x;
    const int b   = blockIdx.x;
    const int wv  = tid >> 6;
    const int ln  = tid & 63;
    const float* pb = probs + (size_t)b * A_TOT;
    u64*    keys    = wskeys   + (size_t)b * KEY_STRIDE;
    float4* boxws_b = wsboxes  + (size_t)b * QTOT;
    u32*    aorder  = wsaorder + (size_t)b * QTOT;

    // ================= Phase A: stable descending score sort =================
    for (int i = tid; i < NB; i += NT) bucketA[i] = 0u;
    __syncthreads();
    for (int j = tid; j < A_TOT; j += NT) {
        float s = pb[j];
        int bkt = (int)(s * (float)NB);
        bkt = (NB-1) - min(max(bkt, 0), NB-1);
        atomicAdd(&bucketA[bkt], 1u);
    }
    __syncthreads();
    {   // exclusive scan, 8 counts/thread + Hillis-Steele over 512
        int base = tid << 3;
        u32 c[8]; u32 mysum = 0;
        #pragma unroll
        for (int i = 0; i < 8; ++i) { c[i] = bucketA[base+i]; mysum += c[i]; }
        stemp[tid] = mysum;
        __syncthreads();
        int src = 0;
        for (int off = 1; off < NT; off <<= 1) {
            u32 v = stemp[src*NT + tid];
            if (tid >= off) v += stemp[src*NT + tid - off];
            stemp[(src^1)*NT + tid] = v;
            __syncthreads();
            src ^= 1;
        }
        u32 run = stemp[src*NT + tid] - mysum;
        #pragma unroll
        for (int i = 0; i < 8; ++i) { bucketA[base+i] = run; bucketB[base+i] = run; run += c[i]; }
    }
    __syncthreads();
    for (int j = tid; j < A_TOT; j += NT) {
        float s = pb[j];
        int bkt = (int)(s * (float)NB);
        bkt = (NB-1) - min(max(bkt, 0), NB-1);
        u32 pos = atomicAdd(&bucketB[bkt], 1u);
        keys[pos] = ((u64)__float_as_uint(s) << 32) | (u64)(~(u32)j);
    }
    __syncthreads();
    for (int bkt = tid; bkt < NB; bkt += NT) {   // per-bucket insertion sort
        int begin = (int)bucketA[bkt], end = (int)bucketB[bkt];
        for (int k = begin + 1; k < end; ++k) {
            u64 key = keys[k];
            int m = k - 1;
            while (m >= begin && keys[m] < key) { keys[m+1] = keys[m]; --m; }
            keys[m+1] = key;
        }
    }
    __syncthreads();

    // ====== Phase B: decode rank-order boxes + area histogram ======
    for (int i = tid; i < NB; i += NT) bucketA[i] = 0u;
    __syncthreads();
    for (int k = 0; k < QTOT/NT; ++k) {
        int r = tid + k*NT;
        if (r < TOPN) {
            u64 kk = keys[r];
            u32 aidx = ~((u32)kk);
            float4 av = *(const float4*)(anchors + (size_t)aidx*4);
            float4 dv = *(const float4*)(deltas + ((size_t)b*A_TOT + aidx)*4);
            float d0 = dv.x*0.1f, d1 = dv.y*0.1f, d2 = dv.z*0.2f, d3 = dv.w*0.2f;
            float ah = av.z - av.x, aw = av.w - av.y;
            float acy = av.x + 0.5f*ah, acx = av.y + 0.5f*aw;
            float h  = (float)exp((double)d2) * ah;   // correctly-rounded fp32 exp
            float w_ = (float)exp((double)d3) * aw;
            float cy = d0*ah + acy;
            float cx = d1*aw + acx;
            float y1 = cy - 0.5f*h, x1 = cx - 0.5f*w_;
            float y2 = cy + 0.5f*h, x2 = cx + 0.5f*w_;
            boxws_b[r] = make_float4(y1, x1, y2, x2);
            float area = (y2 - y1) * (x2 - x1);
            int ab = (int)(area * 1024.0f);
            ab = min(max(ab, 0), NB-1);
            atomicAdd(&bucketA[ab], 1u);
            keys[r] = (kk & 0xFFFFFFFF00000000ull) | (u64)(u32)ab;  // stash bucket
        }
    }
    __syncthreads();
    {   // scan area counts -> cursors in bucketB
        int base = tid << 3;
        u32 c[8]; u32 mysum = 0;
        #pragma unroll
        for (int i = 0; i < 8; ++i) { c[i] = bucketA[base+i]; mysum += c[i]; }
        stemp[tid] = mysum;
        __syncthreads();
        int src = 0;
        for (int off = 1; off < NT; off <<= 1) {
            u32 v = stemp[src*NT + tid];
            if (tid >= off) v += stemp[src*NT + tid - off];
            stemp[(src^1)*NT + tid] = v;
            __syncthreads();
            src ^= 1;
        }
        u32 run = stemp[src*NT + tid] - mysum;
        #pragma unroll
        for (int i = 0; i < 8; ++i) { bucketB[base+i] = run; run += c[i]; }
    }
    __syncthreads();
    // ====== Phase C: area-order scatter ======
    for (int q = TOPN + tid; q < QTOT; q += NT) aorder[q] = 0xFFFFFFFFu;
    for (int k = 0; k < QTOT/NT; ++k) {
        int r = tid + k*NT;
        if (r < TOPN) {
            int ab = (int)(keys[r] & (u64)(NB-1));
            u32 pos = atomicAdd(&bucketB[ab], 1u);
            aorder[pos] = (u32)r;
        }
    }
    __syncthreads();

    // ====== Phase D: load my 12 candidates into REGISTERS (scalars) ======
    DECL_SLOT(0) DECL_SLOT(1) DECL_SLOT(2) DECL_SLOT(3) DECL_SLOT(4) DECL_SLOT(5)
    DECL_SLOT(6) DECL_SLOT(7) DECL_SLOT(8) DECL_SLOT(9) DECL_SLOT(10) DECL_SLOT(11)
    u32 mask = 0;
    u32 aminb = 0x7F800000u, amaxb = 0u;
    FORALL(LOAD_SLOT)
    float wMinA = __uint_as_float((u32)__builtin_amdgcn_readlane(wave_min_dpp((int)aminb), 63));
    float wMaxA = __uint_as_float((u32)__builtin_amdgcn_readlane(wave_max_dpp((int)amaxb), 63));

    // thread-local argmin (key + its box, tracked incrementally)
    u32 tmin; float cby1 = 0.f, cbx1 = 0.f, cby2 = 0.f, cbx2 = 0.f;
    {
        u32 t_ = (u32)SENT_T;
        FORALL(MIN_SLOT)
        tmin = t_;
    }
    {
        u32 wmin = (u32)__builtin_amdgcn_readlane(wave_min_dpp((int)tmin), 63);
        if (ln == 63) wkey[0][wv] = wmin;
        if (tmin == wmin && tmin != (u32)SENT_T)
            wbox[0][wv] = make_float4(cby1, cbx1, cby2, cbx2);
    }
    __syncthreads();

    // ====== greedy NMS: 1 barrier/pick; sel box via tiny LDS record ======
    int par = 0;
    int pend = POST;
    for (int p = 0; p < POST; ++p) {
        uint4 s0 = *((const uint4*)&wkey[par][0]);
        uint4 s1 = *((const uint4*)&wkey[par][4]);
        u32 v = min(min(min(s0.x,s0.y), min(s0.z,s0.w)),
                    min(min(s1.x,s1.y), min(s1.z,s1.w)));
        u32 vu = (u32)__builtin_amdgcn_readfirstlane((int)v);
        if (vu == (u32)SENT_T) { pend = p; break; }
        if (tid == 0) pickrank[p] = vu >> 7;
        float4 sb = wbox[par][vu & 7u];      // winning wave's published box
        float sy1 = sb.x, sx1 = sb.y, sy2 = sb.z, sx2 = sb.w;
        float sA  = (sy2 - sy1) * (sx2 - sx1);
        float loA = 0.699f  * sA;
        float hiA = 1.4307f * sA;
        bool changed = false;
        if (tmin == vu) {                     // I own the pick: retire it
            mask &= ~(1u << ((vu >> 3) & 15u));
            changed = true;
        }
        if (!(wMaxA < loA || wMinA > hiA)) {  // wave-level area quick-reject
            FORALL(TEST_SLOT)
        }
        if (changed) {
            u32 t_ = (u32)SENT_T;
            FORALL(MIN_SLOT)
            tmin = t_;
        }
        u32 wmin = (u32)__builtin_amdgcn_readlane(wave_min_dpp((int)tmin), 63);
        if (ln == 63) wkey[par ^ 1][wv] = wmin;
        if (tmin == wmin && tmin != (u32)SENT_T)
            wbox[par ^ 1][wv] = make_float4(cby1, cbx1, cby2, cbx2);
        __syncthreads();
        par ^= 1;
    }
    __syncthreads();

    // ====== epilogue: parallel coalesced output ======
    const size_t sbase = (size_t)BATCH * POST * 4;
    float4* out4 = (float4*)out;
    for (int p = tid; p < POST; p += NT) {
        size_t row = (size_t)b * POST + p;
        if (p < pend) {
            u32 r = pickrank[p];
            float4 bx = boxws_b[r];
            float4 ob;
            ob.x = fminf(fmaxf(bx.x, 0.f), 1.f);
            ob.y = fminf(fmaxf(bx.y, 0.f), 1.f);
            ob.z = fminf(fmaxf(bx.z, 0.f), 1.f);
            ob.w = fminf(fmaxf(bx.w, 0.f), 1.f);
            out4[row] = ob;
            out[sbase + row] = __uint_as_float((u32)(keys[r] >> 32));
        } else {
            out4[row] = make_float4(0.f, 0.f, 0.f, 0.f);
            out[sbase + row] = 0.f;
        }
    }
}

extern "C" void kernel_launch(void* const* d_in, const int* in_sizes, int n_in,
                              void* d_out, int out_size, void* d_ws, size_t ws_size,
                              hipStream_t stream) {
    const float* deltas  = (const float*)d_in[0];  // [64,31,31,36] f32
    const float* probs   = (const float*)d_in[1];  // [64,31,31,9]  f32
    // d_in[2] = gt_labels (unused)
    const float* anchors = (const float*)d_in[3];  // [8649,4] f32
    float* out = (float*)d_out;                    // 480000 f32

    char* ws = (char*)d_ws;
    u64*    wskeys   = (u64*)ws;                                    // 4,456,448 B
    float4* wsboxes  = (float4*)(ws + (size_t)BATCH*KEY_STRIDE*8);  // 6,291,456 B
    u32*    wsaorder = (u32*)(ws + (size_t)BATCH*KEY_STRIDE*8
                                 + (size_t)BATCH*QTOT*16);          // 1,572,864 B

    roibbox_kernel<<<dim3(BATCH), dim3(NT), 0, stream>>>(
        deltas, probs, anchors, out, wskeys, wsboxes, wsaorder);
}